// Round 9
// baseline (100.412 us; speedup 1.0000x reference)
//
#include <hip/hip_runtime.h>
#include <hip/hip_bf16.h>

#define NB   16384
#define ND   2048
#define NG   8
#define NR   6
#define NKC  48
#define NOUT 54
#define KCW  64                   // k per chunk
#define NCW  (ND / KCW)           // 32 chunks
#define LROW 136                  // tier-3 fallback gemm
#define BM   32
#define KC   128
#define NCH  (ND / KC)
#define MAXT (NB / BM + NG)

typedef __attribute__((ext_vector_type(8))) short short8_t;
typedef __attribute__((ext_vector_type(4))) float f32x4;

__device__ __forceinline__ unsigned short f2bf(float x) {
    union { float f; unsigned u; } v; v.f = x;
    unsigned r = v.u + 0x7FFFu + ((v.u >> 16) & 1u);   // RNE
    return (unsigned short)(r >> 16);
}

__device__ __forceinline__ short8_t cvt8(float4 a, float4 b) {
    short8_t s;
    s[0] = (short)f2bf(a.x); s[1] = (short)f2bf(a.y);
    s[2] = (short)f2bf(a.z); s[3] = (short)f2bf(a.w);
    s[4] = (short)f2bf(b.x); s[5] = (short)f2bf(b.y);
    s[6] = (short)f2bf(b.z); s[7] = (short)f2bf(b.w);
    return s;
}

// hardware async global->LDS, 16B/lane; LDS dest wave-uniform base + lane*16
__device__ __forceinline__ void gl_lds16(const void* g, void* s) {
    __builtin_amdgcn_global_load_lds(
        (const __attribute__((address_space(1))) void*)g,
        (__attribute__((address_space(3))) void*)s,
        16, 0, 0);
}

#define WAITV(N) do { asm volatile("s_waitcnt vmcnt(" #N ")" ::: "memory"); \
                      __builtin_amdgcn_sched_barrier(0); } while (0)

// ---- histogram (tier-3) ----
__global__ void hist_kernel(const int* __restrict__ roi, int* __restrict__ counts) {
    int i = blockIdx.x * 256 + threadIdx.x;
    int g = roi[i];
    int lane = threadIdx.x & 63;
    #pragma unroll
    for (int gg = 0; gg < NG; ++gg) {
        unsigned long long m = __ballot(g == gg);
        if (m && lane == (int)(__ffsll((unsigned long long)m) - 1))
            atomicAdd(&counts[gg], (int)__popcll(m));
    }
}

// ---- scatter into packed regions (tier-3) ----
__global__ void scatter_kernel(const int* __restrict__ roi, const int* __restrict__ counts,
                               int* __restrict__ ranks, int* __restrict__ perm) {
    int off[NG];
    int acc = 0;
    #pragma unroll
    for (int gg = 0; gg < NG; ++gg) { off[gg] = acc; acc += counts[gg]; }
    int i = blockIdx.x * 256 + threadIdx.x;
    int g = roi[i];
    int lane = threadIdx.x & 63;
    #pragma unroll
    for (int gg = 0; gg < NG; ++gg) {
        unsigned long long m = __ballot(g == gg);
        if (!m) continue;
        int leader = (int)(__ffsll((unsigned long long)m) - 1);
        int base = 0;
        if (lane == leader) base = atomicAdd(&ranks[gg], (int)__popcll(m));
        base = __shfl(base, leader);
        if (g == gg) {
            int rank = (int)__popcll(m & ((1ull << lane) - 1ull));
            perm[off[gg] + base + rank] = i;
        }
    }
}

// ---- 1-pass scatter into fixed per-group regions of stride NB (tier-1) ----
__global__ void scatter1_kernel(const int* __restrict__ roi, int* __restrict__ cnt,
                                int* __restrict__ perm) {
    int i = blockIdx.x * 256 + threadIdx.x;
    int g = roi[i];
    int lane = threadIdx.x & 63;
    #pragma unroll
    for (int gg = 0; gg < NG; ++gg) {
        unsigned long long m = __ballot(g == gg);
        if (!m) continue;
        int leader = (int)(__ffsll((unsigned long long)m) - 1);
        int base = 0;
        if (lane == leader) base = atomicAdd(&cnt[gg], (int)__popcll(m));
        base = __shfl(base, leader);
        if (g == gg) {
            int rank = (int)__popcll(m & ((1ull << lane) - 1ull));
            perm[gg * NB + base + rank] = i;
        }
    }
}

// ---- W -> bf16 blob, fragment-major, per (g,chunk) 8KB: seg s=nh*4+n*2+ks ----
// unit u (16B): l=u&63, ks=(u>>6)&1, n=(u>>7)&1, nh=(u>>8)&1, c=(u>>9)&31, g=u>>14
// content = W[g][nh*32 + n*16 + (l&15)][c*64 + ks*32 + (l>>4)*8 .. +8)
__global__ void wconv_kernel(const float* __restrict__ Wreg, const float* __restrict__ Wcls,
                             short* __restrict__ Wbf) {
    int u = blockIdx.x * 256 + threadIdx.x;          // 131072 units
    int l  = u & 63;
    int ks = (u >> 6) & 1;
    int n  = (u >> 7) & 1;
    int nh = (u >> 8) & 1;
    int c  = (u >> 9) & 31;
    int g  = u >> 14;
    int row = nh * 32 + n * 16 + (l & 15);
    int k   = c * 64 + ks * 32 + (l >> 4) * 8;
    short8_t v = {0, 0, 0, 0, 0, 0, 0, 0};
    if (row < NOUT) {
        const float* s = (row < NR) ? Wreg + (size_t)(g * NR + row) * ND + k
                                    : Wcls + (size_t)(g * NKC + row - NR) * ND + k;
        float4 a = *(const float4*)s;
        float4 b = *(const float4*)(s + 4);
        v = cvt8(a, b);
    }
    *(short8_t*)(Wbf + (size_t)u * 8) = v;
}

// ---- primary: wave-autonomous pipelined GEMM, coalesced A staging, no barriers ----
// 256 blocks x 4 waves; wave w owns 16-sample tile t = blockIdx.x + w*256 (+1024).
// Per chunk: A reg-staged (full-line coalesced) -> swizzled ds_write; B via
// contiguous global_load_lds from blob into ring-3; counted vmcnt, never 0 mid-loop.
__launch_bounds__(256, 1)
__global__ void gemm_wa_kernel(const float* __restrict__ feats,
                               const short* __restrict__ Wbf,
                               const float* __restrict__ breg, const float* __restrict__ bcls,
                               const int* __restrict__ counts, const int* __restrict__ perm,
                               float* __restrict__ out, int stride) {
    __shared__ __align__(16) char lds[4][4096 + 3 * 8192];   // per wave: A 4KB | B ring-3
    int tid = threadIdx.x, w = tid >> 6, l = tid & 63, lr = l & 15, lq = l >> 4;
    char* A0 = &lds[w][0];
    char* B0 = &lds[w][4096];

    int ts[NG + 1]; ts[0] = 0;
    int off[NG]; int acc_ = 0;
    #pragma unroll
    for (int gg = 0; gg < NG; ++gg) {
        int c = counts[gg];
        off[gg] = stride ? gg * stride : acc_;
        acc_ += c;
        ts[gg + 1] = ts[gg] + (c + 15) / 16;
    }
    int NT = ts[NG];

    // A write/read address precompute (lane-invariant parts)
    const int segA = (l & 1) * 1024;                       // j=0,1 segment
    const int sxA  = ((l >> 2) & 15) * 64 + ((l >> 1) & 1) * 16;
    const int raA  = (lr * 4 + lq) * 16;                   // fragment read slot*16

    for (int t = blockIdx.x + w * 256; t < NT; t += 1024) {
        int g = 0;
        #pragma unroll
        for (int gg = 0; gg < NG; ++gg) if (t >= ts[gg + 1]) g = gg + 1;
        int gcnt  = counts[g];
        int goff  = off[g];
        int rbase = (t - ts[g]) * 16;
        int nv = gcnt - rbase; if (nv > 16) nv = 16;

        int ar_ = rbase + (l >> 2); if (ar_ >= gcnt) ar_ = gcnt - 1;   // clamp
        const float* aB = feats + (size_t)perm[goff + ar_] * ND + (l & 3) * 4;
        const short* bB = Wbf + (size_t)g * 131072 + l * 8;

        f32x4 acc0 = {0,0,0,0}, acc1 = {0,0,0,0}, acc2 = {0,0,0,0}, acc3 = {0,0,0,0};
        float4 ar0, ar1, ar2, ar3;

#define LDA(cc) do { const float* a_ = aB + (cc) * KCW;                        \
        ar0 = *(const float4*)(a_);      ar1 = *(const float4*)(a_ + 16);      \
        ar2 = *(const float4*)(a_ + 32); ar3 = *(const float4*)(a_ + 48); } while (0)
#define GLB(cc, sl_) do { const short* b_ = bB + (size_t)(cc) * 4096;          \
        char* d_ = B0 + (sl_) * 8192;                                          \
        gl_lds16(b_,        d_);        gl_lds16(b_ +  512, d_ + 1024);        \
        gl_lds16(b_ + 1024, d_ + 2048); gl_lds16(b_ + 1536, d_ + 3072);        \
        gl_lds16(b_ + 2048, d_ + 4096); gl_lds16(b_ + 2560, d_ + 5120);        \
        gl_lds16(b_ + 3072, d_ + 6144); gl_lds16(b_ + 3584, d_ + 7168); } while (0)
#define WRA() do {                                                             \
        *(float4*)(A0 + segA + sxA)        = ar0;                              \
        *(float4*)(A0 + segA + sxA + 32)   = ar1;                              \
        *(float4*)(A0 + segA + 2048 + sxA)      = ar2;                         \
        *(float4*)(A0 + segA + 2048 + sxA + 32) = ar3; } while (0)

        LDA(0);
        GLB(0, 0); GLB(1, 1);

        int sl = 0;
        for (int c = 0; c < NCW; ++c) {
            int sln = sl + 2; if (sln >= 3) sln -= 3;
            if (c < NCW - 2) GLB(c + 2, sln);
            if (c == 0)           WAITV(16);
            else if (c < NCW - 2) WAITV(8);
            else                  WAITV(0);
            WRA();                                   // A(c) regs -> LDS
            if (c < NCW - 1) LDA(c + 1);             // prefetch next A into regs
            const char* Bc = B0 + sl * 8192;
            #pragma unroll
            for (int ks = 0; ks < 2; ++ks) {
                float4 a0 = *(const float4*)(A0 + ks * 2048 + raA);
                float4 a1 = *(const float4*)(A0 + ks * 2048 + 1024 + raA);
                short8_t af = cvt8(a0, a1);
                short8_t b0 = *(const short8_t*)(Bc + (0 * 2 + ks) * 1024 + l * 16);
                short8_t b1 = *(const short8_t*)(Bc + (1 * 2 + ks) * 1024 + l * 16);
                short8_t b2 = *(const short8_t*)(Bc + (2 * 2 + ks) * 1024 + l * 16);
                short8_t b3 = *(const short8_t*)(Bc + (3 * 2 + ks) * 1024 + l * 16);
                acc0 = __builtin_amdgcn_mfma_f32_16x16x32_bf16(af, b0, acc0, 0, 0, 0);
                acc1 = __builtin_amdgcn_mfma_f32_16x16x32_bf16(af, b1, acc1, 0, 0, 0);
                acc2 = __builtin_amdgcn_mfma_f32_16x16x32_bf16(af, b2, acc2, 0, 0, 0);
                acc3 = __builtin_amdgcn_mfma_f32_16x16x32_bf16(af, b3, acc3, 0, 0, 0);
            }
            sl = (sl == 2) ? 0 : sl + 1;
        }
#undef LDA
#undef GLB
#undef WRA

        const int B6 = NB * NR;
        #pragma unroll
        for (int n = 0; n < 4; ++n) {
            f32x4 v = (n == 0) ? acc0 : (n == 1) ? acc1 : (n == 2) ? acc2 : acc3;
            int col = n * 16 + lr;
            if (col < NOUT) {
                #pragma unroll
                for (int j = 0; j < 4; ++j) {
                    int row = lq * 4 + j;
                    if (row < nv) {
                        int s2 = perm[goff + rbase + row];
                        if (col < NR) out[s2 * NR + col] = v[j] + breg[g * NR + col];
                        else          out[B6 + s2 * NKC + (col - NR)] = v[j] + bcls[g * NKC + (col - NR)];
                    }
                }
            }
        }
    }
}

// ---- tier-3 GEMM (proven R3 path, no blob needed) ----
__launch_bounds__(256, 3)
__global__ void gemm_kernel(const float* __restrict__ feats,
                            const float* __restrict__ Wreg, const float* __restrict__ breg,
                            const float* __restrict__ Wcls, const float* __restrict__ bcls,
                            const int* __restrict__ counts, const int* __restrict__ perm,
                            float* __restrict__ out, int stride) {
    __shared__ __align__(16) short Bsh[2][64][LROW];
    __shared__ int sRow[BM];

    int ts[NG + 1]; ts[0] = 0;
    int off[NG]; int acc = 0;
    #pragma unroll
    for (int gg = 0; gg < NG; ++gg) {
        int c = counts[gg];
        off[gg] = stride ? gg * stride : acc;
        acc += c;
        ts[gg + 1] = ts[gg] + (c + BM - 1) / BM;
    }
    int b = blockIdx.x;
    if (b >= ts[NG]) return;
    int g = 0;
    #pragma unroll
    for (int gg = 0; gg < NG; ++gg) if (b >= ts[gg + 1]) g = gg + 1;
    int gcnt  = counts[g];
    int goff  = off[g];
    int rbase = (b - ts[g]) * BM;
    int nvalid = gcnt - rbase; if (nvalid > BM) nvalid = BM;

    int tid = threadIdx.x;
    if (tid < BM) {
        int r = rbase + tid;
        if (r >= gcnt) r = gcnt - 1;
        sRow[tid] = perm[goff + r];
    }
    __syncthreads();

    int rB = tid >> 2;
    int cq = tid & 3;
    const float* wsrc = nullptr;
    if (rB < NR)        wsrc = Wreg + ((size_t)g * NR + rB) * ND + cq * 32;
    else if (rB < NOUT) wsrc = Wcls + ((size_t)g * NKC + (rB - NR)) * ND + cq * 32;

    int w = tid >> 6, l = tid & 63, lr = l & 15, lq = l >> 4;
    int mt = w & 1, nh = w >> 1;
    const float* aptr = feats + (size_t)sRow[mt * 16 + lr] * ND + lq * 8;
    const short* brp = (const short*)&Bsh[0][0][0] + (nh * 32 + lr) * LROW + lq * 8;

    f32x4 acc0 = {0, 0, 0, 0}, acc1 = {0, 0, 0, 0};
    float4 rb[8];

    if (wsrc) {
        #pragma unroll
        for (int i = 0; i < 8; ++i) rb[i] = *(const float4*)(wsrc + 4 * i);
    } else {
        #pragma unroll
        for (int i = 0; i < 8; ++i) rb[i] = make_float4(0.f, 0.f, 0.f, 0.f);
    }
    {
        short* bw = &Bsh[0][rB][cq * 32];
        #pragma unroll
        for (int j = 0; j < 4; ++j) *(short8_t*)(bw + 8 * j) = cvt8(rb[2 * j], rb[2 * j + 1]);
    }
    __syncthreads();

    #pragma unroll
    for (int c = 0; c < NCH; ++c) {
        const int cur = c & 1, nxt = cur ^ 1;
        if (c + 1 < NCH && wsrc) {
            const float* s = wsrc + (c + 1) * KC;
            #pragma unroll
            for (int i = 0; i < 8; ++i) rb[i] = *(const float4*)(s + 4 * i);
        }
        const short* bp = brp + cur * (64 * LROW);
        const float* ap = aptr + c * KC;
        #pragma unroll
        for (int ks = 0; ks < 4; ++ks) {
            float4 a0 = *(const float4*)(ap + ks * 32);
            float4 a1 = *(const float4*)(ap + ks * 32 + 4);
            short8_t af = cvt8(a0, a1);
            short8_t b0 = *(const short8_t*)(bp + ks * 32);
            short8_t b1 = *(const short8_t*)(bp + 16 * LROW + ks * 32);
            acc0 = __builtin_amdgcn_mfma_f32_16x16x32_bf16(af, b0, acc0, 0, 0, 0);
            acc1 = __builtin_amdgcn_mfma_f32_16x16x32_bf16(af, b1, acc1, 0, 0, 0);
        }
        if (c + 1 < NCH && wsrc) {
            short* bw = &Bsh[nxt][rB][cq * 32];
            #pragma unroll
            for (int j = 0; j < 4; ++j) *(short8_t*)(bw + 8 * j) = cvt8(rb[2 * j], rb[2 * j + 1]);
        } else if (c + 1 < NCH) {
            short8_t z = {0,0,0,0,0,0,0,0};
            short* bw = &Bsh[nxt][rB][cq * 32];
            #pragma unroll
            for (int j = 0; j < 4; ++j) *(short8_t*)(bw + 8 * j) = z;
        }
        __syncthreads();
    }

    const int B6 = NB * NR;
    #pragma unroll
    for (int n = 0; n < 2; ++n) {
        f32x4 v = n ? acc1 : acc0;
        int col = nh * 32 + n * 16 + lr;
        if (col < NOUT) {
            #pragma unroll
            for (int j = 0; j < 4; ++j) {
                int row = mt * 16 + lq * 4 + j;
                if (row < nvalid) {
                    int smp = sRow[row];
                    if (col < NR) out[smp * NR + col] = v[j] + breg[g * NR + col];
                    else          out[B6 + smp * NKC + (col - NR)] = v[j] + bcls[g * NKC + (col - NR)];
                }
            }
        }
    }
}

// ---- tier-4: exact fp32, one wave per sample ----
__global__ void fallback_kernel(const float* __restrict__ feats, const int* __restrict__ roi,
                                const float* __restrict__ Wreg, const float* __restrict__ breg,
                                const float* __restrict__ Wcls, const float* __restrict__ bcls,
                                float* __restrict__ out) {
    int i = blockIdx.x;
    int lane = threadIdx.x;
    int g = roi[i];
    const float* frow = feats + (size_t)i * ND;
    float f[32];
    #pragma unroll
    for (int q = 0; q < 32; ++q) f[q] = frow[lane + 64 * q];
    for (int o = 0; o < NOUT; ++o) {
        const float* wrow = (o < NR) ? Wreg + ((size_t)g * NR + o) * ND
                                     : Wcls + ((size_t)g * NKC + (o - NR)) * ND;
        float p = 0.f;
        #pragma unroll
        for (int q = 0; q < 32; ++q) p += f[q] * wrow[lane + 64 * q];
        #pragma unroll
        for (int s = 32; s; s >>= 1) p += __shfl_xor(p, s);
        if (lane == 0) {
            if (o < NR) out[i * NR + o] = p + breg[g * NR + o];
            else        out[NB * NR + i * NKC + (o - NR)] = p + bcls[g * NKC + (o - NR)];
        }
    }
}

extern "C" void kernel_launch(void* const* d_in, const int* in_sizes, int n_in,
                              void* d_out, int out_size, void* d_ws, size_t ws_size,
                              hipStream_t stream) {
    const float* feats = (const float*)d_in[0];
    const int*   roi   = (const int*)d_in[1];
    const float* Wreg  = (const float*)d_in[2];
    const float* breg  = (const float*)d_in[3];
    const float* Wcls  = (const float*)d_in[4];
    const float* bcls  = (const float*)d_in[5];
    float* out = (float*)d_out;

    const size_t wbfBytes = (size_t)NG * 131072 * 2;              // 2 MB blob
    const size_t need_t1 = wbfBytes + 256 + (size_t)NG * NB * 4;  // blob + 1-pass perm
    const size_t need_t3 = 256 + (size_t)NB * 4;                  // packed-perm path

    if (ws_size >= need_t1) {
        short* Wbf = (short*)d_ws;
        int* cnt  = (int*)((char*)d_ws + wbfBytes);
        int* perm = cnt + 64;
        hipMemsetAsync(cnt, 0, 8 * sizeof(int), stream);
        wconv_kernel<<<512, 256, 0, stream>>>(Wreg, Wcls, Wbf);
        scatter1_kernel<<<NB / 256, 256, 0, stream>>>(roi, cnt, perm);
        gemm_wa_kernel<<<256, 256, 0, stream>>>(feats, Wbf, breg, bcls, cnt, perm, out, NB);
    } else if (ws_size >= need_t3) {
        int* counts = (int*)d_ws;
        int* ranks  = counts + 8;
        int* perm   = counts + 64;
        hipMemsetAsync(counts, 0, 16 * sizeof(int), stream);
        hist_kernel<<<NB / 256, 256, 0, stream>>>(roi, counts);
        scatter_kernel<<<NB / 256, 256, 0, stream>>>(roi, counts, ranks, perm);
        gemm_kernel<<<MAXT, 256, 0, stream>>>(feats, Wreg, breg, Wcls, bcls, counts, perm, out, 0);
    } else {
        fallback_kernel<<<NB, 64, 0, stream>>>(feats, roi, Wreg, breg, Wcls, bcls, out);
    }
}

// Round 10
// 85.710 us; speedup vs baseline: 1.1715x; 1.1715x over previous
//
#include <hip/hip_runtime.h>
#include <hip/hip_bf16.h>

#define NB   16384
#define ND   2048
#define NG   8
#define NR   6
#define NKC  48
#define NOUT 54
#define MAXTILES (NB / 64 + NG)   // 264
#define LROW 136                  // tier-3 fallback gemm
#define BM   32
#define KC   128
#define NCH  (ND / KC)
#define MAXT (NB / BM + NG)

typedef __attribute__((ext_vector_type(8))) short short8_t;
typedef __attribute__((ext_vector_type(4))) float f32x4;

__device__ __forceinline__ unsigned short f2bf(float x) {
    union { float f; unsigned u; } v; v.f = x;
    unsigned r = v.u + 0x7FFFu + ((v.u >> 16) & 1u);   // RNE
    return (unsigned short)(r >> 16);
}

__device__ __forceinline__ short8_t cvt8(float4 a, float4 b) {
    short8_t s;
    s[0] = (short)f2bf(a.x); s[1] = (short)f2bf(a.y);
    s[2] = (short)f2bf(a.z); s[3] = (short)f2bf(a.w);
    s[4] = (short)f2bf(b.x); s[5] = (short)f2bf(b.y);
    s[6] = (short)f2bf(b.z); s[7] = (short)f2bf(b.w);
    return s;
}

__device__ __forceinline__ void gl_lds16(const void* g, void* s) {
    __builtin_amdgcn_global_load_lds(
        (const __attribute__((address_space(1))) void*)g,
        (__attribute__((address_space(3))) void*)s,
        16, 0, 0);
}

#define WAITV(N) do { asm volatile("s_waitcnt vmcnt(" #N ")" ::: "memory"); \
                      __builtin_amdgcn_sched_barrier(0); } while (0)
#define BAR() do { __builtin_amdgcn_s_barrier(); \
                   __builtin_amdgcn_sched_barrier(0); } while (0)
#define SBAR() __builtin_amdgcn_sched_barrier(0)

// ---- histogram (tier-3) ----
__global__ void hist_kernel(const int* __restrict__ roi, int* __restrict__ counts) {
    int i = blockIdx.x * 256 + threadIdx.x;
    int g = roi[i];
    int lane = threadIdx.x & 63;
    #pragma unroll
    for (int gg = 0; gg < NG; ++gg) {
        unsigned long long m = __ballot(g == gg);
        if (m && lane == (int)(__ffsll((unsigned long long)m) - 1))
            atomicAdd(&counts[gg], (int)__popcll(m));
    }
}

// ---- scatter into packed regions (tier-3) ----
__global__ void scatter_kernel(const int* __restrict__ roi, const int* __restrict__ counts,
                               int* __restrict__ ranks, int* __restrict__ perm) {
    int off[NG];
    int acc = 0;
    #pragma unroll
    for (int gg = 0; gg < NG; ++gg) { off[gg] = acc; acc += counts[gg]; }
    int i = blockIdx.x * 256 + threadIdx.x;
    int g = roi[i];
    int lane = threadIdx.x & 63;
    #pragma unroll
    for (int gg = 0; gg < NG; ++gg) {
        unsigned long long m = __ballot(g == gg);
        if (!m) continue;
        int leader = (int)(__ffsll((unsigned long long)m) - 1);
        int base = 0;
        if (lane == leader) base = atomicAdd(&ranks[gg], (int)__popcll(m));
        base = __shfl(base, leader);
        if (g == gg) {
            int rank = (int)__popcll(m & ((1ull << lane) - 1ull));
            perm[off[gg] + base + rank] = i;
        }
    }
}

// ---- 1-pass scatter into fixed per-group regions of stride NB (tier-1) ----
__global__ void scatter1_kernel(const int* __restrict__ roi, int* __restrict__ cnt,
                                int* __restrict__ perm) {
    int i = blockIdx.x * 256 + threadIdx.x;
    int g = roi[i];
    int lane = threadIdx.x & 63;
    #pragma unroll
    for (int gg = 0; gg < NG; ++gg) {
        unsigned long long m = __ballot(g == gg);
        if (!m) continue;
        int leader = (int)(__ffsll((unsigned long long)m) - 1);
        int base = 0;
        if (lane == leader) base = atomicAdd(&cnt[gg], (int)__popcll(m));
        base = __shfl(base, leader);
        if (g == gg) {
            int rank = (int)__popcll(m & ((1ull << lane) - 1ull));
            perm[gg * NB + base + rank] = i;
        }
    }
}

// ---- W -> bf16 blob: [g][kslice8][chunk4][seg8][lane64] 16B units ----
// seg = nh*4 + nf*2 + k2; content = W[g][nh*32+nf*16+(l&15)][ksl*256 + c*64 + k2*32 + (l>>4)*8 ..+8)
__global__ void wconv2_kernel(const float* __restrict__ Wreg, const float* __restrict__ Wcls,
                              short* __restrict__ Wbf) {
    int u = blockIdx.x * 256 + threadIdx.x;          // 131072 units
    int l   = u & 63;
    int seg = (u >> 6) & 7;
    int c   = (u >> 9) & 3;
    int ksl = (u >> 11) & 7;
    int g   = u >> 14;
    int nh = seg >> 2, nf = (seg >> 1) & 1, k2 = seg & 1;
    int row = nh * 32 + nf * 16 + (l & 15);
    int k   = ksl * 256 + c * 64 + k2 * 32 + (l >> 4) * 8;
    short8_t v = {0, 0, 0, 0, 0, 0, 0, 0};
    if (row < NOUT) {
        const float* s = (row < NR) ? Wreg + (size_t)(g * NR + row) * ND + k
                                    : Wcls + (size_t)(g * NKC + row - NR) * ND + k;
        float4 a = *(const float4*)s;
        float4 b = *(const float4*)(s + 4);
        v = cvt8(a, b);
    }
    *(short8_t*)(Wbf + (size_t)u * 8) = v;
}

// ---- primary: persistent-B grouped GEMM, K-split 8, counted-vmcnt A pipeline ----
// 512 blocks: b -> (g = b>>6, ks = (b>>3)&7, sub = b&7). Block holds B-slice
// (64 cols x 256 k, 32KB) in LDS for its whole life; streams ~4 same-group
// 64-row tiles; A ring-3 16KB slots staged 256B-contiguous with XOR swizzle.
__launch_bounds__(256, 2)
__global__ void gemm_ps_kernel(const float* __restrict__ feats,
                               const short* __restrict__ Wbf,
                               const int* __restrict__ cnt,
                               const int* __restrict__ perm,
                               float* __restrict__ partials) {
    __shared__ __align__(16) char lds[81920];   // A ring-3 @0 (3x16KB), B @49152 (32KB)
    const char* fb = (const char*)feats;

    int tid = threadIdx.x, w = tid >> 6, l = tid & 63, lr = l & 15, lq = l >> 4;
    int mt = w & 1, nh = w >> 1;
    int b = blockIdx.x;
    int g = b >> 6, ks = (b >> 3) & 7, sub = b & 7;
    int cg = cnt[g];
    int tg = (cg + 63) >> 6;
    int per = (tg + 7) >> 3;
    int j0 = sub * per, j1 = min(j0 + per, tg);
    if (j0 >= j1) return;
    int tsg = 0;
    #pragma unroll
    for (int gg = 0; gg < NG; ++gg) if (gg < g) tsg += (cnt[gg] + 63) >> 6;

    const int gbase = g * NB;
    const int ksb   = ks * 1024;                      // byte offset of kslice in a row
    const int lx7   = lr & 7;
    const int lrow  = l >> 4;                         // 0..3
    const int kkE   = (((l & 15) ^ (lrow & 7)) << 4);
    const int kkO   = (((l & 15) ^ ((4 + lrow) & 7)) << 4);
    const int rowb0 = (mt * 8 + (lr >> 2)) * 1024 + (lr & 3) * 256;
    const int rowb1 = rowb0 + 4096;
    const int bo0   = nh * 4096;
    const int bo1   = nh * 4096 + 2048;

#define STAGE_A(cc, sl) do { size_t co_ = (size_t)(ksb + (cc) * 256);          \
        gl_lds16(fb + ab0 + co_, lds + (sl) * 16384 + (w * 4 + 0) * 1024);     \
        gl_lds16(fb + ab1 + co_, lds + (sl) * 16384 + (w * 4 + 1) * 1024);     \
        gl_lds16(fb + ab2 + co_, lds + (sl) * 16384 + (w * 4 + 2) * 1024);     \
        gl_lds16(fb + ab3 + co_, lds + (sl) * 16384 + (w * 4 + 3) * 1024);     \
    } while (0)

#define CSTEP(cc, k2) do {                                                     \
        const char* Ab_ = lds + csl * 16384;                                   \
        const char* Bb_ = lds + 49152 + (cc) * 8192 + ((k2) << 10) + l * 16;   \
        float4 x0 = *(const float4*)(Ab_ + rowb0 + ((((k2)*8 + lq*2 + 0) ^ lx7) << 4)); \
        float4 x1 = *(const float4*)(Ab_ + rowb0 + ((((k2)*8 + lq*2 + 1) ^ lx7) << 4)); \
        float4 y0 = *(const float4*)(Ab_ + rowb1 + ((((k2)*8 + lq*2 + 0) ^ lx7) << 4)); \
        float4 y1 = *(const float4*)(Ab_ + rowb1 + ((((k2)*8 + lq*2 + 1) ^ lx7) << 4)); \
        short8_t af0 = cvt8(x0, x1), af1 = cvt8(y0, y1);                       \
        short8_t b0 = *(const short8_t*)(Bb_ + bo0);                           \
        short8_t b1 = *(const short8_t*)(Bb_ + bo1);                           \
        acc00 = __builtin_amdgcn_mfma_f32_16x16x32_bf16(af0, b0, acc00, 0, 0, 0); \
        acc01 = __builtin_amdgcn_mfma_f32_16x16x32_bf16(af0, b1, acc01, 0, 0, 0); \
        acc10 = __builtin_amdgcn_mfma_f32_16x16x32_bf16(af1, b0, acc10, 0, 0, 0); \
        acc11 = __builtin_amdgcn_mfma_f32_16x16x32_bf16(af1, b1, acc11, 0, 0, 0); \
    } while (0)

#define COMPUTE(cc) do { CSTEP(cc, 0); CSTEP(cc, 1); csl = (csl == 2) ? 0 : csl + 1; } while (0)

    // ---- prologue: first tile perm, B-slice, A chunks 0..2 ----
    int rb = j0 * 64;
    int q0 = rb + w * 16 + 0  + lrow; if (q0 >= cg) q0 = cg - 1;
    int q1 = rb + w * 16 + 4  + lrow; if (q1 >= cg) q1 = cg - 1;
    int q2 = rb + w * 16 + 8  + lrow; if (q2 >= cg) q2 = cg - 1;
    int q3 = rb + w * 16 + 12 + lrow; if (q3 >= cg) q3 = cg - 1;
    size_t ab0 = (size_t)perm[gbase + q0] * 8192 + kkE;
    size_t ab1 = (size_t)perm[gbase + q1] * 8192 + kkO;
    size_t ab2 = (size_t)perm[gbase + q2] * 8192 + kkE;
    size_t ab3 = (size_t)perm[gbase + q3] * 8192 + kkO;

    {   // B-slice: wave w stages chunk c=w (8 x 1KB contiguous)
        const char* wb = (const char*)Wbf
            + (((size_t)(g * 8 + ks) * 4 + w) * 8) * 1024 + l * 16;
        #pragma unroll
        for (int jj = 0; jj < 8; ++jj)
            gl_lds16(wb + jj * 1024, lds + 49152 + (w * 8 + jj) * 1024);
    }
    SBAR();
    STAGE_A(0, 0); STAGE_A(1, 1); STAGE_A(2, 2);

    f32x4 acc00 = {0,0,0,0}, acc01 = {0,0,0,0}, acc10 = {0,0,0,0}, acc11 = {0,0,0,0};
    int csl = 0, ssl = 0;

    for (int jt = j0; jt < j1; ++jt) {
        int tGlob = tsg + jt;
        // phase 0
        WAITV(8); BAR();
        COMPUTE(0); BAR();
        STAGE_A(3, ssl); ssl = (ssl == 2) ? 0 : ssl + 1;
        SBAR();
        // next-tile perm loads (dummy = current tile on last)
        int nrb = (jt + 1 < j1) ? (jt + 1) * 64 : rb;
        int n0 = nrb + w * 16 + 0  + lrow; if (n0 >= cg) n0 = cg - 1;
        int n1 = nrb + w * 16 + 4  + lrow; if (n1 >= cg) n1 = cg - 1;
        int n2 = nrb + w * 16 + 8  + lrow; if (n2 >= cg) n2 = cg - 1;
        int n3 = nrb + w * 16 + 12 + lrow; if (n3 >= cg) n3 = cg - 1;
        int pn0 = perm[gbase + n0];
        int pn1 = perm[gbase + n1];
        int pn2 = perm[gbase + n2];
        int pn3 = perm[gbase + n3];
        SBAR();
        // phases 1..3
        WAITV(12); BAR(); COMPUTE(1); BAR();
        WAITV(8);  BAR(); COMPUTE(2); BAR();
        WAITV(4);  BAR(); COMPUTE(3); BAR();
        // stores (16 per thread) -> partials
        {
            float* pt = partials + (size_t)tGlob * 32768 + ks * 64 + nh * 32 + lr;
            int rowc = mt * 32 + lq * 4;
            #pragma unroll
            for (int f = 0; f < 2; ++f) {
                f32x4 v0 = f ? acc10 : acc00;
                f32x4 v1 = f ? acc11 : acc01;
                #pragma unroll
                for (int j = 0; j < 4; ++j) {
                    size_t ro = (size_t)(rowc + f * 16 + j) * 512;
                    pt[ro]      = v0[j];
                    pt[ro + 16] = v1[j];
                }
            }
        }
        acc00 = (f32x4){0,0,0,0}; acc01 = (f32x4){0,0,0,0};
        acc10 = (f32x4){0,0,0,0}; acc11 = (f32x4){0,0,0,0};
        SBAR();
        if (jt + 1 < j1) {
            rb = (jt + 1) * 64;
            ab0 = (size_t)pn0 * 8192 + kkE;
            ab1 = (size_t)pn1 * 8192 + kkO;
            ab2 = (size_t)pn2 * 8192 + kkE;
            ab3 = (size_t)pn3 * 8192 + kkO;
            STAGE_A(0, ssl); ssl = (ssl == 2) ? 0 : ssl + 1;
            STAGE_A(1, ssl); ssl = (ssl == 2) ? 0 : ssl + 1;
            STAGE_A(2, ssl); ssl = (ssl == 2) ? 0 : ssl + 1;
        }
    }
#undef STAGE_A
#undef CSTEP
#undef COMPUTE
}

// ---- reduce: sum 8 K-slices, add bias, scatter to routed output rows ----
__global__ void reduce_kernel(const float* __restrict__ partials,
                              const int* __restrict__ cnt, const int* __restrict__ perm,
                              const float* __restrict__ breg, const float* __restrict__ bcls,
                              float* __restrict__ out) {
    int t = blockIdx.x;
    int base = 0, gsel = -1, rbase = 0;
    #pragma unroll
    for (int gg = 0; gg < NG; ++gg) {
        int tgg = (cnt[gg] + 63) >> 6;
        if (gsel < 0 && t < base + tgg) { gsel = gg; rbase = (t - base) * 64; }
        base += tgg;
    }
    if (gsel < 0) return;
    int nv = cnt[gsel] - rbase; if (nv > 64) nv = 64;
    int r = threadIdx.x >> 2, cq = threadIdx.x & 3;
    if (r >= nv) return;

    const f32x4* pb = (const f32x4*)(partials + (size_t)t * 32768 + (size_t)r * 512 + cq * 16);
    f32x4 s0 = {0,0,0,0}, s1 = {0,0,0,0}, s2 = {0,0,0,0}, s3 = {0,0,0,0};
    #pragma unroll
    for (int ksl = 0; ksl < 8; ++ksl) {
        const f32x4* p = pb + ksl * 16;   // 64 floats = 16 f32x4 per slice row
        s0 += p[0]; s1 += p[1]; s2 += p[2]; s3 += p[3];
    }
    int smp = perm[gsel * NB + rbase + r];
    const int B6 = NB * NR;
    #pragma unroll
    for (int e = 0; e < 16; ++e) {
        int col = cq * 16 + e;
        float v = (e < 4) ? s0[e] : (e < 8) ? s1[e - 4] : (e < 12) ? s2[e - 8] : s3[e - 12];
        if (col < NR)        out[smp * NR + col] = v + breg[gsel * NR + col];
        else if (col < NOUT) out[B6 + smp * NKC + (col - NR)] = v + bcls[gsel * NKC + (col - NR)];
    }
}

// ---- tier-3 GEMM (proven R3 path, no blob needed) ----
__launch_bounds__(256, 3)
__global__ void gemm_kernel(const float* __restrict__ feats,
                            const float* __restrict__ Wreg, const float* __restrict__ breg,
                            const float* __restrict__ Wcls, const float* __restrict__ bcls,
                            const int* __restrict__ counts, const int* __restrict__ perm,
                            float* __restrict__ out, int stride) {
    __shared__ __align__(16) short Bsh[2][64][LROW];
    __shared__ int sRow[BM];

    int ts[NG + 1]; ts[0] = 0;
    int off[NG]; int acc = 0;
    #pragma unroll
    for (int gg = 0; gg < NG; ++gg) {
        int c = counts[gg];
        off[gg] = stride ? gg * stride : acc;
        acc += c;
        ts[gg + 1] = ts[gg] + (c + BM - 1) / BM;
    }
    int b = blockIdx.x;
    if (b >= ts[NG]) return;
    int g = 0;
    #pragma unroll
    for (int gg = 0; gg < NG; ++gg) if (b >= ts[gg + 1]) g = gg + 1;
    int gcnt  = counts[g];
    int goff  = off[g];
    int rbase = (b - ts[g]) * BM;
    int nvalid = gcnt - rbase; if (nvalid > BM) nvalid = BM;

    int tid = threadIdx.x;
    if (tid < BM) {
        int r = rbase + tid;
        if (r >= gcnt) r = gcnt - 1;
        sRow[tid] = perm[goff + r];
    }
    __syncthreads();

    int rB = tid >> 2;
    int cq = tid & 3;
    const float* wsrc = nullptr;
    if (rB < NR)        wsrc = Wreg + ((size_t)g * NR + rB) * ND + cq * 32;
    else if (rB < NOUT) wsrc = Wcls + ((size_t)g * NKC + (rB - NR)) * ND + cq * 32;

    int w = tid >> 6, l = tid & 63, lr = l & 15, lq = l >> 4;
    int mt = w & 1, nh = w >> 1;
    const float* aptr = feats + (size_t)sRow[mt * 16 + lr] * ND + lq * 8;
    const short* brp = (const short*)&Bsh[0][0][0] + (nh * 32 + lr) * LROW + lq * 8;

    f32x4 acc0 = {0, 0, 0, 0}, acc1 = {0, 0, 0, 0};
    float4 rb[8];

    if (wsrc) {
        #pragma unroll
        for (int i = 0; i < 8; ++i) rb[i] = *(const float4*)(wsrc + 4 * i);
    } else {
        #pragma unroll
        for (int i = 0; i < 8; ++i) rb[i] = make_float4(0.f, 0.f, 0.f, 0.f);
    }
    {
        short* bw = &Bsh[0][rB][cq * 32];
        #pragma unroll
        for (int j = 0; j < 4; ++j) *(short8_t*)(bw + 8 * j) = cvt8(rb[2 * j], rb[2 * j + 1]);
    }
    __syncthreads();

    #pragma unroll
    for (int c = 0; c < NCH; ++c) {
        const int cur = c & 1, nxt = cur ^ 1;
        if (c + 1 < NCH && wsrc) {
            const float* s = wsrc + (c + 1) * KC;
            #pragma unroll
            for (int i = 0; i < 8; ++i) rb[i] = *(const float4*)(s + 4 * i);
        }
        const short* bp = brp + cur * (64 * LROW);
        const float* ap = aptr + c * KC;
        #pragma unroll
        for (int ks = 0; ks < 4; ++ks) {
            float4 a0 = *(const float4*)(ap + ks * 32);
            float4 a1 = *(const float4*)(ap + ks * 32 + 4);
            short8_t af = cvt8(a0, a1);
            short8_t b0 = *(const short8_t*)(bp + ks * 32);
            short8_t b1 = *(const short8_t*)(bp + 16 * LROW + ks * 32);
            acc0 = __builtin_amdgcn_mfma_f32_16x16x32_bf16(af, b0, acc0, 0, 0, 0);
            acc1 = __builtin_amdgcn_mfma_f32_16x16x32_bf16(af, b1, acc1, 0, 0, 0);
        }
        if (c + 1 < NCH && wsrc) {
            short* bw = &Bsh[nxt][rB][cq * 32];
            #pragma unroll
            for (int j = 0; j < 4; ++j) *(short8_t*)(bw + 8 * j) = cvt8(rb[2 * j], rb[2 * j + 1]);
        } else if (c + 1 < NCH) {
            short8_t z = {0,0,0,0,0,0,0,0};
            short* bw = &Bsh[nxt][rB][cq * 32];
            #pragma unroll
            for (int j = 0; j < 4; ++j) *(short8_t*)(bw + 8 * j) = z;
        }
        __syncthreads();
    }

    const int B6 = NB * NR;
    #pragma unroll
    for (int n = 0; n < 2; ++n) {
        f32x4 v = n ? acc1 : acc0;
        int col = nh * 32 + n * 16 + lr;
        if (col < NOUT) {
            #pragma unroll
            for (int j = 0; j < 4; ++j) {
                int row = mt * 16 + lq * 4 + j;
                if (row < nvalid) {
                    int smp = sRow[row];
                    if (col < NR) out[smp * NR + col] = v[j] + breg[g * NR + col];
                    else          out[B6 + smp * NKC + (col - NR)] = v[j] + bcls[g * NKC + (col - NR)];
                }
            }
        }
    }
}

// ---- tier-4: exact fp32, one wave per sample ----
__global__ void fallback_kernel(const float* __restrict__ feats, const int* __restrict__ roi,
                                const float* __restrict__ Wreg, const float* __restrict__ breg,
                                const float* __restrict__ Wcls, const float* __restrict__ bcls,
                                float* __restrict__ out) {
    int i = blockIdx.x;
    int lane = threadIdx.x;
    int g = roi[i];
    const float* frow = feats + (size_t)i * ND;
    float f[32];
    #pragma unroll
    for (int q = 0; q < 32; ++q) f[q] = frow[lane + 64 * q];
    for (int o = 0; o < NOUT; ++o) {
        const float* wrow = (o < NR) ? Wreg + ((size_t)g * NR + o) * ND
                                     : Wcls + ((size_t)g * NKC + (o - NR)) * ND;
        float p = 0.f;
        #pragma unroll
        for (int q = 0; q < 32; ++q) p += f[q] * wrow[lane + 64 * q];
        #pragma unroll
        for (int s = 32; s; s >>= 1) p += __shfl_xor(p, s);
        if (lane == 0) {
            if (o < NR) out[i * NR + o] = p + breg[g * NR + o];
            else        out[NB * NR + i * NKC + (o - NR)] = p + bcls[g * NKC + (o - NR)];
        }
    }
}

extern "C" void kernel_launch(void* const* d_in, const int* in_sizes, int n_in,
                              void* d_out, int out_size, void* d_ws, size_t ws_size,
                              hipStream_t stream) {
    const float* feats = (const float*)d_in[0];
    const int*   roi   = (const int*)d_in[1];
    const float* Wreg  = (const float*)d_in[2];
    const float* breg  = (const float*)d_in[3];
    const float* Wcls  = (const float*)d_in[4];
    const float* bcls  = (const float*)d_in[5];
    float* out = (float*)d_out;

    const size_t wbfBytes  = (size_t)NG * 131072 * 2;               // 2 MB blob
    const size_t partOff   = 3u * 1024 * 1024;                      // partials at +3MB
    const size_t partBytes = (size_t)MAXTILES * 32768 * 4;          // 34.6 MB
    const size_t need_t1   = partOff + partBytes;
    const size_t need_t3   = 256 + (size_t)NB * 4;

    if (ws_size >= need_t1) {
        short* Wbf      = (short*)d_ws;
        int*   cnt      = (int*)((char*)d_ws + wbfBytes);
        int*   perm     = cnt + 64;                                 // NG*NB ints (512KB)
        float* partials = (float*)((char*)d_ws + partOff);
        hipMemsetAsync(cnt, 0, 8 * sizeof(int), stream);
        wconv2_kernel<<<512, 256, 0, stream>>>(Wreg, Wcls, Wbf);
        scatter1_kernel<<<NB / 256, 256, 0, stream>>>(roi, cnt, perm);
        gemm_ps_kernel<<<512, 256, 0, stream>>>(feats, Wbf, cnt, perm, partials);
        reduce_kernel<<<MAXTILES, 256, 0, stream>>>(partials, cnt, perm, breg, bcls, out);
    } else if (ws_size >= need_t3) {
        int* counts = (int*)d_ws;
        int* ranks  = counts + 8;
        int* perm   = counts + 64;
        hipMemsetAsync(counts, 0, 16 * sizeof(int), stream);
        hist_kernel<<<NB / 256, 256, 0, stream>>>(roi, counts);
        scatter_kernel<<<NB / 256, 256, 0, stream>>>(roi, counts, ranks, perm);
        gemm_kernel<<<MAXT, 256, 0, stream>>>(feats, Wreg, breg, Wcls, bcls, counts, perm, out, 0);
    } else {
        fallback_kernel<<<NB, 64, 0, stream>>>(feats, roi, Wreg, breg, Wcls, bcls, out);
    }
}

// Round 11
// 72.188 us; speedup vs baseline: 1.3910x; 1.1873x over previous
//
#include <hip/hip_runtime.h>
#include <hip/hip_bf16.h>

#define NB   16384
#define ND   2048
#define NG   8
#define NR   6
#define NKC  48
#define NOUT 54
#define KW   512                  // K per wave (4 waves split ND)
#define NT16 (NB / 16 + NG)       // 1032 tiles of 16 samples
#define LROW 136                  // tier-3 fallback gemm
#define BM   32
#define KC   128
#define NCH  (ND / KC)
#define MAXT (NB / BM + NG)

typedef __attribute__((ext_vector_type(8))) short short8_t;
typedef __attribute__((ext_vector_type(4))) float f32x4;

__device__ __forceinline__ unsigned short f2bf(float x) {
    union { float f; unsigned u; } v; v.f = x;
    unsigned r = v.u + 0x7FFFu + ((v.u >> 16) & 1u);   // RNE
    return (unsigned short)(r >> 16);
}

__device__ __forceinline__ short8_t cvt8(float4 a, float4 b) {
    short8_t s;
    s[0] = (short)f2bf(a.x); s[1] = (short)f2bf(a.y);
    s[2] = (short)f2bf(a.z); s[3] = (short)f2bf(a.w);
    s[4] = (short)f2bf(b.x); s[5] = (short)f2bf(b.y);
    s[6] = (short)f2bf(b.z); s[7] = (short)f2bf(b.w);
    return s;
}

__device__ __forceinline__ short8_t as_s8(float4 v) {
    union { float4 f; short8_t s; } u; u.f = v; return u.s;
}

#define WAITV(N) do { asm volatile("s_waitcnt vmcnt(" #N ")" ::: "memory"); \
                      __builtin_amdgcn_sched_barrier(0); } while (0)

// ---- histogram (tier-3) ----
__global__ void hist_kernel(const int* __restrict__ roi, int* __restrict__ counts) {
    int i = blockIdx.x * 256 + threadIdx.x;
    int g = roi[i];
    int lane = threadIdx.x & 63;
    #pragma unroll
    for (int gg = 0; gg < NG; ++gg) {
        unsigned long long m = __ballot(g == gg);
        if (m && lane == (int)(__ffsll((unsigned long long)m) - 1))
            atomicAdd(&counts[gg], (int)__popcll(m));
    }
}

// ---- scatter into packed regions (tier-3) ----
__global__ void scatter_kernel(const int* __restrict__ roi, const int* __restrict__ counts,
                               int* __restrict__ ranks, int* __restrict__ perm) {
    int off[NG];
    int acc = 0;
    #pragma unroll
    for (int gg = 0; gg < NG; ++gg) { off[gg] = acc; acc += counts[gg]; }
    int i = blockIdx.x * 256 + threadIdx.x;
    int g = roi[i];
    int lane = threadIdx.x & 63;
    #pragma unroll
    for (int gg = 0; gg < NG; ++gg) {
        unsigned long long m = __ballot(g == gg);
        if (!m) continue;
        int leader = (int)(__ffsll((unsigned long long)m) - 1);
        int base = 0;
        if (lane == leader) base = atomicAdd(&ranks[gg], (int)__popcll(m));
        base = __shfl(base, leader);
        if (g == gg) {
            int rank = (int)__popcll(m & ((1ull << lane) - 1ull));
            perm[off[gg] + base + rank] = i;
        }
    }
}

// ---- 1-pass scatter into fixed per-group regions of stride NB (tier-1) ----
__global__ void scatter1_kernel(const int* __restrict__ roi, int* __restrict__ cnt,
                                int* __restrict__ perm) {
    int i = blockIdx.x * 256 + threadIdx.x;
    int g = roi[i];
    int lane = threadIdx.x & 63;
    #pragma unroll
    for (int gg = 0; gg < NG; ++gg) {
        unsigned long long m = __ballot(g == gg);
        if (!m) continue;
        int leader = (int)(__ffsll((unsigned long long)m) - 1);
        int base = 0;
        if (lane == leader) base = atomicAdd(&cnt[gg], (int)__popcll(m));
        base = __shfl(base, leader);
        if (g == gg) {
            int rank = (int)__popcll(m & ((1ull << lane) - 1ull));
            perm[gg * NB + base + rank] = i;
        }
    }
}

// ---- W -> bf16 blob, fragment-major, per (g,chunk) 8KB contiguous ----
// unit u (16B): l=u&63, q=(u>>6)&7, c=(u>>9)&31, g=u>>14; n=q>>1, ks=q&1
// content = W[g][n*16+(l&15)][c*64 + ks*32 + (l>>4)*8 .. +8)
__global__ void wconv_kernel(const float* __restrict__ Wreg, const float* __restrict__ Wcls,
                             short* __restrict__ Wbf) {
    int u = blockIdx.x * 256 + threadIdx.x;          // 131072 units
    int l = u & 63;
    int q = (u >> 6) & 7;
    int c = (u >> 9) & 31;
    int g = u >> 14;
    int n = q >> 1, ks = q & 1;
    int row = n * 16 + (l & 15);
    int k   = c * 64 + ks * 32 + (l >> 4) * 8;
    short8_t v = {0, 0, 0, 0, 0, 0, 0, 0};
    if (row < NOUT) {
        const float* s = (row < NR) ? Wreg + (size_t)(g * NR + row) * ND + k
                                    : Wcls + (size_t)(g * NKC + row - NR) * ND + k;
        float4 a = *(const float4*)s;
        float4 b = *(const float4*)(s + 4);
        v = cvt8(a, b);
    }
    *(short8_t*)(Wbf + (size_t)u * 8) = v;
}

// ---- primary: K-split GEMM with inline-asm pinned load pipeline ----
// 1032 blocks x 4 waves; wave w does K [512w, 512w+512) for its block's 16
// samples. 8 chunks of KC=64; A (4 loads) + B (8 loads) per chunk issued as
// asm volatile global_load_dwordx4, double-buffered; s_waitcnt vmcnt(12) +
// sched_barrier(0) before each consume (chunk c+1 stays in flight). No LDS
// in the K-loop, no barriers; LDS reduce of 4 K-partials at the end.
__launch_bounds__(256, 3)
__global__ void gemm_asm_kernel(const float* __restrict__ feats,
                                const short* __restrict__ Wbf,
                                const float* __restrict__ breg, const float* __restrict__ bcls,
                                const int* __restrict__ counts, const int* __restrict__ perm,
                                float* __restrict__ out, int stride) {
    __shared__ float sacc[3][16][66];   // +2 pad

    int tid = threadIdx.x, w = tid >> 6, l = tid & 63, lr = l & 15, lq = l >> 4;
    int t = blockIdx.x;

    int ts[NG + 1]; ts[0] = 0;
    int off[NG]; int acc_ = 0;
    #pragma unroll
    for (int gg = 0; gg < NG; ++gg) {
        int c = counts[gg];
        off[gg] = stride ? gg * stride : acc_;
        acc_ += c;
        ts[gg + 1] = ts[gg] + (c + 15) / 16;
    }
    if (t >= ts[NG]) return;
    int g = 0;
    #pragma unroll
    for (int gg = 0; gg < NG; ++gg) if (t >= ts[gg + 1]) g = gg + 1;
    int gcnt  = counts[g];
    int goff  = off[g];
    int rbase = (t - ts[g]) * 16;
    int nvalid = gcnt - rbase; if (nvalid > 16) nvalid = 16;

    int r = rbase + lr; if (r >= gcnt) r = gcnt - 1;   // clamp; stores masked later
    int smp = perm[goff + r];
    const char* aB = (const char*)(feats + (size_t)smp * ND + w * KW + lq * 8);
    const char* bB = (const char*)(Wbf + (size_t)g * 131072 + (size_t)w * 8 * 4096 + l * 8);

    f32x4 acc0 = {0,0,0,0}, acc1 = {0,0,0,0}, acc2 = {0,0,0,0}, acc3 = {0,0,0,0};
    float4 xa0, xa1, xa2, xa3, ya0, ya1, ya2, ya3;
    float4 xb0, xb1, xb2, xb3, xb4, xb5, xb6, xb7;
    float4 yb0, yb1, yb2, yb3, yb4, yb5, yb6, yb7;

#define ISSUE(cc, P) do {                                                               \
        const char* a_ = aB + (cc) * 256;                                               \
        asm volatile("global_load_dwordx4 %0, %1, off"            : "=v"(P##a0) : "v"(a_) : "memory"); \
        asm volatile("global_load_dwordx4 %0, %1, off offset:16"  : "=v"(P##a1) : "v"(a_) : "memory"); \
        asm volatile("global_load_dwordx4 %0, %1, off offset:128" : "=v"(P##a2) : "v"(a_) : "memory"); \
        asm volatile("global_load_dwordx4 %0, %1, off offset:144" : "=v"(P##a3) : "v"(a_) : "memory"); \
        const char* b_  = bB + (cc) * 8192;                                             \
        const char* b2_ = b_ + 4096;                                                    \
        asm volatile("global_load_dwordx4 %0, %1, off"             : "=v"(P##b0) : "v"(b_)  : "memory"); \
        asm volatile("global_load_dwordx4 %0, %1, off offset:1024" : "=v"(P##b1) : "v"(b_)  : "memory"); \
        asm volatile("global_load_dwordx4 %0, %1, off offset:2048" : "=v"(P##b2) : "v"(b_)  : "memory"); \
        asm volatile("global_load_dwordx4 %0, %1, off offset:3072" : "=v"(P##b3) : "v"(b_)  : "memory"); \
        asm volatile("global_load_dwordx4 %0, %1, off"             : "=v"(P##b4) : "v"(b2_) : "memory"); \
        asm volatile("global_load_dwordx4 %0, %1, off offset:1024" : "=v"(P##b5) : "v"(b2_) : "memory"); \
        asm volatile("global_load_dwordx4 %0, %1, off offset:2048" : "=v"(P##b6) : "v"(b2_) : "memory"); \
        asm volatile("global_load_dwordx4 %0, %1, off offset:3072" : "=v"(P##b7) : "v"(b2_) : "memory"); \
    } while (0)

#define CMP(P) do {                                                                     \
        short8_t af0 = cvt8(P##a0, P##a1), af1 = cvt8(P##a2, P##a3);                    \
        acc0 = __builtin_amdgcn_mfma_f32_16x16x32_bf16(af0, as_s8(P##b0), acc0, 0, 0, 0); \
        acc1 = __builtin_amdgcn_mfma_f32_16x16x32_bf16(af0, as_s8(P##b2), acc1, 0, 0, 0); \
        acc2 = __builtin_amdgcn_mfma_f32_16x16x32_bf16(af0, as_s8(P##b4), acc2, 0, 0, 0); \
        acc3 = __builtin_amdgcn_mfma_f32_16x16x32_bf16(af0, as_s8(P##b6), acc3, 0, 0, 0); \
        acc0 = __builtin_amdgcn_mfma_f32_16x16x32_bf16(af1, as_s8(P##b1), acc0, 0, 0, 0); \
        acc1 = __builtin_amdgcn_mfma_f32_16x16x32_bf16(af1, as_s8(P##b3), acc1, 0, 0, 0); \
        acc2 = __builtin_amdgcn_mfma_f32_16x16x32_bf16(af1, as_s8(P##b5), acc2, 0, 0, 0); \
        acc3 = __builtin_amdgcn_mfma_f32_16x16x32_bf16(af1, as_s8(P##b7), acc3, 0, 0, 0); \
    } while (0)

    ISSUE(0, x); ISSUE(1, y);          // 24 loads in flight
    WAITV(12); CMP(x); ISSUE(2, x);    // chunk 0 landed; 1,2 in flight
    WAITV(12); CMP(y); ISSUE(3, y);
    WAITV(12); CMP(x); ISSUE(4, x);
    WAITV(12); CMP(y); ISSUE(5, y);
    WAITV(12); CMP(x); ISSUE(6, x);
    WAITV(12); CMP(y); ISSUE(7, y);
    WAITV(12); CMP(x);
    WAITV(0);  CMP(y);
#undef ISSUE
#undef CMP

    // waves 1..3 park partials in LDS
    if (w > 0) {
        #pragma unroll
        for (int n = 0; n < 4; ++n) {
            f32x4 v = (n == 0) ? acc0 : (n == 1) ? acc1 : (n == 2) ? acc2 : acc3;
            #pragma unroll
            for (int j = 0; j < 4; ++j)
                sacc[w - 1][lq * 4 + j][n * 16 + lr] = v[j];
        }
    }
    __syncthreads();

    if (w == 0) {
        const int B6 = NB * NR;
        #pragma unroll
        for (int n = 0; n < 4; ++n) {
            f32x4 a = (n == 0) ? acc0 : (n == 1) ? acc1 : (n == 2) ? acc2 : acc3;
            int col = n * 16 + lr;
            if (col < NOUT) {
                #pragma unroll
                for (int j = 0; j < 4; ++j) {
                    int row = lq * 4 + j;
                    if (row < nvalid) {
                        float v = a[j] + sacc[0][row][col] + sacc[1][row][col] + sacc[2][row][col];
                        int s2 = perm[goff + rbase + row];
                        if (col < NR) out[s2 * NR + col] = v + breg[g * NR + col];
                        else          out[B6 + s2 * NKC + (col - NR)] = v + bcls[g * NKC + (col - NR)];
                    }
                }
            }
        }
    }
}

// ---- tier-3 GEMM (proven R3 path, no blob needed) ----
__launch_bounds__(256, 3)
__global__ void gemm_kernel(const float* __restrict__ feats,
                            const float* __restrict__ Wreg, const float* __restrict__ breg,
                            const float* __restrict__ Wcls, const float* __restrict__ bcls,
                            const int* __restrict__ counts, const int* __restrict__ perm,
                            float* __restrict__ out, int stride) {
    __shared__ __align__(16) short Bsh[2][64][LROW];
    __shared__ int sRow[BM];

    int ts[NG + 1]; ts[0] = 0;
    int off[NG]; int acc = 0;
    #pragma unroll
    for (int gg = 0; gg < NG; ++gg) {
        int c = counts[gg];
        off[gg] = stride ? gg * stride : acc;
        acc += c;
        ts[gg + 1] = ts[gg] + (c + BM - 1) / BM;
    }
    int b = blockIdx.x;
    if (b >= ts[NG]) return;
    int g = 0;
    #pragma unroll
    for (int gg = 0; gg < NG; ++gg) if (b >= ts[gg + 1]) g = gg + 1;
    int gcnt  = counts[g];
    int goff  = off[g];
    int rbase = (b - ts[g]) * BM;
    int nvalid = gcnt - rbase; if (nvalid > BM) nvalid = BM;

    int tid = threadIdx.x;
    if (tid < BM) {
        int r = rbase + tid;
        if (r >= gcnt) r = gcnt - 1;
        sRow[tid] = perm[goff + r];
    }
    __syncthreads();

    int rB = tid >> 2;
    int cq = tid & 3;
    const float* wsrc = nullptr;
    if (rB < NR)        wsrc = Wreg + ((size_t)g * NR + rB) * ND + cq * 32;
    else if (rB < NOUT) wsrc = Wcls + ((size_t)g * NKC + (rB - NR)) * ND + cq * 32;

    int w = tid >> 6, l = tid & 63, lr = l & 15, lq = l >> 4;
    int mt = w & 1, nh = w >> 1;
    const float* aptr = feats + (size_t)sRow[mt * 16 + lr] * ND + lq * 8;
    const short* brp = (const short*)&Bsh[0][0][0] + (nh * 32 + lr) * LROW + lq * 8;

    f32x4 acc0 = {0, 0, 0, 0}, acc1 = {0, 0, 0, 0};
    float4 rb[8];

    if (wsrc) {
        #pragma unroll
        for (int i = 0; i < 8; ++i) rb[i] = *(const float4*)(wsrc + 4 * i);
    } else {
        #pragma unroll
        for (int i = 0; i < 8; ++i) rb[i] = make_float4(0.f, 0.f, 0.f, 0.f);
    }
    {
        short* bw = &Bsh[0][rB][cq * 32];
        #pragma unroll
        for (int j = 0; j < 4; ++j) *(short8_t*)(bw + 8 * j) = cvt8(rb[2 * j], rb[2 * j + 1]);
    }
    __syncthreads();

    #pragma unroll
    for (int c = 0; c < NCH; ++c) {
        const int cur = c & 1, nxt = cur ^ 1;
        if (c + 1 < NCH && wsrc) {
            const float* s = wsrc + (c + 1) * KC;
            #pragma unroll
            for (int i = 0; i < 8; ++i) rb[i] = *(const float4*)(s + 4 * i);
        }
        const short* bp = brp + cur * (64 * LROW);
        const float* ap = aptr + c * KC;
        #pragma unroll
        for (int ks = 0; ks < 4; ++ks) {
            float4 a0 = *(const float4*)(ap + ks * 32);
            float4 a1 = *(const float4*)(ap + ks * 32 + 4);
            short8_t af = cvt8(a0, a1);
            short8_t b0 = *(const short8_t*)(bp + ks * 32);
            short8_t b1 = *(const short8_t*)(bp + 16 * LROW + ks * 32);
            acc0 = __builtin_amdgcn_mfma_f32_16x16x32_bf16(af, b0, acc0, 0, 0, 0);
            acc1 = __builtin_amdgcn_mfma_f32_16x16x32_bf16(af, b1, acc1, 0, 0, 0);
        }
        if (c + 1 < NCH && wsrc) {
            short* bw = &Bsh[nxt][rB][cq * 32];
            #pragma unroll
            for (int j = 0; j < 4; ++j) *(short8_t*)(bw + 8 * j) = cvt8(rb[2 * j], rb[2 * j + 1]);
        } else if (c + 1 < NCH) {
            short8_t z = {0,0,0,0,0,0,0,0};
            short* bw = &Bsh[nxt][rB][cq * 32];
            #pragma unroll
            for (int j = 0; j < 4; ++j) *(short8_t*)(bw + 8 * j) = z;
        }
        __syncthreads();
    }

    const int B6 = NB * NR;
    #pragma unroll
    for (int n = 0; n < 2; ++n) {
        f32x4 v = n ? acc1 : acc0;
        int col = nh * 32 + n * 16 + lr;
        if (col < NOUT) {
            #pragma unroll
            for (int j = 0; j < 4; ++j) {
                int row = mt * 16 + lq * 4 + j;
                if (row < nvalid) {
                    int smp = sRow[row];
                    if (col < NR) out[smp * NR + col] = v[j] + breg[g * NR + col];
                    else          out[B6 + smp * NKC + (col - NR)] = v[j] + bcls[g * NKC + (col - NR)];
                }
            }
        }
    }
}

// ---- tier-4: exact fp32, one wave per sample ----
__global__ void fallback_kernel(const float* __restrict__ feats, const int* __restrict__ roi,
                                const float* __restrict__ Wreg, const float* __restrict__ breg,
                                const float* __restrict__ Wcls, const float* __restrict__ bcls,
                                float* __restrict__ out) {
    int i = blockIdx.x;
    int lane = threadIdx.x;
    int g = roi[i];
    const float* frow = feats + (size_t)i * ND;
    float f[32];
    #pragma unroll
    for (int q = 0; q < 32; ++q) f[q] = frow[lane + 64 * q];
    for (int o = 0; o < NOUT; ++o) {
        const float* wrow = (o < NR) ? Wreg + ((size_t)g * NR + o) * ND
                                     : Wcls + ((size_t)g * NKC + (o - NR)) * ND;
        float p = 0.f;
        #pragma unroll
        for (int q = 0; q < 32; ++q) p += f[q] * wrow[lane + 64 * q];
        #pragma unroll
        for (int s = 32; s; s >>= 1) p += __shfl_xor(p, s);
        if (lane == 0) {
            if (o < NR) out[i * NR + o] = p + breg[g * NR + o];
            else        out[NB * NR + i * NKC + (o - NR)] = p + bcls[g * NKC + (o - NR)];
        }
    }
}

extern "C" void kernel_launch(void* const* d_in, const int* in_sizes, int n_in,
                              void* d_out, int out_size, void* d_ws, size_t ws_size,
                              hipStream_t stream) {
    const float* feats = (const float*)d_in[0];
    const int*   roi   = (const int*)d_in[1];
    const float* Wreg  = (const float*)d_in[2];
    const float* breg  = (const float*)d_in[3];
    const float* Wcls  = (const float*)d_in[4];
    const float* bcls  = (const float*)d_in[5];
    float* out = (float*)d_out;

    const size_t wbfBytes = (size_t)NG * 131072 * 2;              // 2 MB blob
    const size_t need_t1 = wbfBytes + 256 + (size_t)NG * NB * 4;  // blob + 1-pass perm
    const size_t need_t3 = 256 + (size_t)NB * 4;                  // packed-perm path

    if (ws_size >= need_t1) {
        short* Wbf = (short*)d_ws;
        int* cnt  = (int*)((char*)d_ws + wbfBytes);
        int* perm = cnt + 64;
        hipMemsetAsync(cnt, 0, 8 * sizeof(int), stream);
        wconv_kernel<<<512, 256, 0, stream>>>(Wreg, Wcls, Wbf);
        scatter1_kernel<<<NB / 256, 256, 0, stream>>>(roi, cnt, perm);
        gemm_asm_kernel<<<NT16, 256, 0, stream>>>(feats, Wbf, breg, bcls, cnt, perm, out, NB);
    } else if (ws_size >= need_t3) {
        int* counts = (int*)d_ws;
        int* ranks  = counts + 8;
        int* perm   = counts + 64;
        hipMemsetAsync(counts, 0, 16 * sizeof(int), stream);
        hist_kernel<<<NB / 256, 256, 0, stream>>>(roi, counts);
        scatter_kernel<<<NB / 256, 256, 0, stream>>>(roi, counts, ranks, perm);
        gemm_kernel<<<MAXT, 256, 0, stream>>>(feats, Wreg, breg, Wcls, bcls, counts, perm, out, 0);
    } else {
        fallback_kernel<<<NB, 64, 0, stream>>>(feats, roi, Wreg, breg, Wcls, bcls, out);
    }
}

// Round 12
// 69.745 us; speedup vs baseline: 1.4397x; 1.0350x over previous
//
#include <hip/hip_runtime.h>
#include <hip/hip_bf16.h>

#define NB   16384
#define ND   2048
#define NG   8
#define NR   6
#define NKC  48
#define NOUT 54
#define LROW 136                  // tier-3 fallback gemm
#define BM   32
#define KC   128
#define NCH  (ND / KC)
#define MAXT (NB / BM + NG)

typedef __attribute__((ext_vector_type(8))) short short8_t;
typedef __attribute__((ext_vector_type(4))) float f32x4;

__device__ __forceinline__ unsigned short f2bf(float x) {
    union { float f; unsigned u; } v; v.f = x;
    unsigned r = v.u + 0x7FFFu + ((v.u >> 16) & 1u);   // RNE
    return (unsigned short)(r >> 16);
}

__device__ __forceinline__ short8_t cvt8(float4 a, float4 b) {
    short8_t s;
    s[0] = (short)f2bf(a.x); s[1] = (short)f2bf(a.y);
    s[2] = (short)f2bf(a.z); s[3] = (short)f2bf(a.w);
    s[4] = (short)f2bf(b.x); s[5] = (short)f2bf(b.y);
    s[6] = (short)f2bf(b.z); s[7] = (short)f2bf(b.w);
    return s;
}

__device__ __forceinline__ void gl_lds16(const void* g, void* s) {
    __builtin_amdgcn_global_load_lds(
        (const __attribute__((address_space(1))) void*)g,
        (__attribute__((address_space(3))) void*)s,
        16, 0, 0);
}

#define WAITV(N) do { asm volatile("s_waitcnt vmcnt(" #N ")" ::: "memory"); \
                      __builtin_amdgcn_sched_barrier(0); } while (0)
#define BAR() do { __builtin_amdgcn_s_barrier(); \
                   __builtin_amdgcn_sched_barrier(0); } while (0)

// ---- histogram (tier-3) ----
__global__ void hist_kernel(const int* __restrict__ roi, int* __restrict__ counts) {
    int i = blockIdx.x * 256 + threadIdx.x;
    int g = roi[i];
    int lane = threadIdx.x & 63;
    #pragma unroll
    for (int gg = 0; gg < NG; ++gg) {
        unsigned long long m = __ballot(g == gg);
        if (m && lane == (int)(__ffsll((unsigned long long)m) - 1))
            atomicAdd(&counts[gg], (int)__popcll(m));
    }
}

// ---- scatter into packed regions (tier-3) ----
__global__ void scatter_kernel(const int* __restrict__ roi, const int* __restrict__ counts,
                               int* __restrict__ ranks, int* __restrict__ perm) {
    int off[NG];
    int acc = 0;
    #pragma unroll
    for (int gg = 0; gg < NG; ++gg) { off[gg] = acc; acc += counts[gg]; }
    int i = blockIdx.x * 256 + threadIdx.x;
    int g = roi[i];
    int lane = threadIdx.x & 63;
    #pragma unroll
    for (int gg = 0; gg < NG; ++gg) {
        unsigned long long m = __ballot(g == gg);
        if (!m) continue;
        int leader = (int)(__ffsll((unsigned long long)m) - 1);
        int base = 0;
        if (lane == leader) base = atomicAdd(&ranks[gg], (int)__popcll(m));
        base = __shfl(base, leader);
        if (g == gg) {
            int rank = (int)__popcll(m & ((1ull << lane) - 1ull));
            perm[off[gg] + base + rank] = i;
        }
    }
}

// ---- merged pre-pass: blocks 0..63 scatter roi into per-group regions;
//      blocks 64..575 convert W into the fragment-major bf16 blob ----
// blob unit u (16B): l=u&63, q=(u>>6)&7, c=(u>>9)&31, g=u>>14; nh=q>>2, nf=(q>>1)&1, ks=q&1
// content = W[g][nh*32 + nf*16 + (l&15)][c*64 + ks*32 + (l>>4)*8 .. +8)
__global__ void prep_kernel(const int* __restrict__ roi, int* __restrict__ cnt,
                            int* __restrict__ perm,
                            const float* __restrict__ Wreg, const float* __restrict__ Wcls,
                            short* __restrict__ Wbf) {
    if (blockIdx.x < 64) {
        int i = blockIdx.x * 256 + threadIdx.x;
        int g = roi[i];
        int lane = threadIdx.x & 63;
        #pragma unroll
        for (int gg = 0; gg < NG; ++gg) {
            unsigned long long m = __ballot(g == gg);
            if (!m) continue;
            int leader = (int)(__ffsll((unsigned long long)m) - 1);
            int base = 0;
            if (lane == leader) base = atomicAdd(&cnt[gg], (int)__popcll(m));
            base = __shfl(base, leader);
            if (g == gg) {
                int rank = (int)__popcll(m & ((1ull << lane) - 1ull));
                perm[gg * NB + base + rank] = i;
            }
        }
    } else {
        int u = (blockIdx.x - 64) * 256 + threadIdx.x;   // 131072 units
        int l = u & 63;
        int q = (u >> 6) & 7;
        int c = (u >> 9) & 31;
        int g = u >> 14;
        int nh = q >> 2, nf = (q >> 1) & 1, ks = q & 1;
        int row = nh * 32 + nf * 16 + (l & 15);
        int k   = c * 64 + ks * 32 + (l >> 4) * 8;
        short8_t v = {0, 0, 0, 0, 0, 0, 0, 0};
        if (row < NOUT) {
            const float* s = (row < NR) ? Wreg + (size_t)(g * NR + row) * ND + k
                                        : Wcls + (size_t)(g * NKC + row - NR) * ND + k;
            float4 a = *(const float4*)s;
            float4 b = *(const float4*)(s + 4);
            v = cvt8(a, b);
        }
        *(short8_t*)(Wbf + (size_t)u * 8) = v;
    }
}

// ---- primary: work-queue grouped GEMM, contiguous A staging, R8 vmcnt discipline ----
// 512 persistent blocks x 8 waves (512 thr). Tile = 64 samples x 64 cols, K=2048
// in 32 chunks of KC=64. A chunk = 64 rows x 256B staged by 16 gl_lds, each
// covering 4 rows x 256B CONTIGUOUS (pre-swizzled source, swizzled read).
// B chunk = 8KB from blob, fully contiguous. Ring-3 slots, WAITV(6) steady.
__launch_bounds__(512, 4)
__global__ void gemm_q_kernel(const float* __restrict__ feats,
                              const short* __restrict__ Wbf,
                              const float* __restrict__ breg, const float* __restrict__ bcls,
                              const int* __restrict__ cnt, const int* __restrict__ perm,
                              int* __restrict__ qhead, float* __restrict__ out) {
    __shared__ __align__(16) char lds[3][24576];   // slot: A 16KB @0 | B 8KB @16384
    __shared__ int sRow[64];
    __shared__ int sTile;

    int tid = threadIdx.x, w = tid >> 6, l = tid & 63, lr = l & 15, lq = l >> 4;
    int mt = w >> 1, nh = w & 1;

    int ts[NG + 1]; ts[0] = 0;
    #pragma unroll
    for (int gg = 0; gg < NG; ++gg) ts[gg + 1] = ts[gg] + ((cnt[gg] + 63) >> 6);
    const int Ttot = ts[NG];

    // loop-invariant read offsets (rule #20: named, statically selected)
    const int key   = lr & 7;
    const int rbyt  = mt * 4096 + lr * 256;
    const int o00 = (((lq * 2 + 0) ^ key) << 4);
    const int o01 = (((lq * 2 + 1) ^ key) << 4);
    const int o10 = (((8 + lq * 2 + 0) ^ key) << 4);
    const int o11 = (((8 + lq * 2 + 1) ^ key) << 4);
    // staging row indices + swizzled source piece offsets
    const int r0 = (2 * w + 0) * 4 + lq;          // rows 0..63 (j=0)
    const int r1 = (2 * w + 1) * 4 + lq;          // (j=1)
    const int sp0 = (((l & 15) ^ (r0 & 7)) << 4);
    const int sp1 = (((l & 15) ^ (r1 & 7)) << 4);
    const int B6 = NB * NR;

    for (;;) {
        if (tid == 0) sTile = atomicAdd(qhead, 1);
        __syncthreads();
        int t = sTile;
        if (t >= Ttot) break;

        int g = 0;
        #pragma unroll
        for (int gg = 0; gg < NG; ++gg) if (t >= ts[gg + 1]) g = gg + 1;
        int cg = cnt[g];
        int rbase = (t - ts[g]) * 64;
        int nv = cg - rbase; if (nv > 64) nv = 64;

        if (tid < 64) {
            int r = rbase + tid;
            if (r >= cg) r = cg - 1;    // clamp; stores masked by nv
            sRow[tid] = perm[g * NB + r];
        }
        __syncthreads();

        const char* a0c = (const char*)(feats + (size_t)sRow[r0] * ND) + sp0;
        const char* a1c = (const char*)(feats + (size_t)sRow[r1] * ND) + sp1;
        const char* bB  = (const char*)Wbf + (size_t)g * 262144 + w * 1024 + l * 16;

#define STAGE(cc, sl) do {                                                     \
        size_t co_ = (size_t)(cc) * 256;                                       \
        gl_lds16(a0c + co_, &lds[sl][w * 2048]);                               \
        gl_lds16(a1c + co_, &lds[sl][w * 2048 + 1024]);                        \
        gl_lds16(bB + (size_t)(cc) * 8192, &lds[sl][16384 + w * 1024]);        \
    } while (0)

#define CSTEP(ks, o_0, o_1) do {                                               \
        const char* Ab_ = &lds[csl][0] + rbyt;                                 \
        const char* Bb_ = &lds[csl][16384] + nh * 4096 + (ks) * 1024 + l * 16; \
        float4 x0 = *(const float4*)(Ab_ + (ks) * 0 + o_0);                    \
        float4 x1 = *(const float4*)(Ab_ + o_1);                               \
        short8_t af = cvt8(x0, x1);                                            \
        short8_t b0 = *(const short8_t*)(Bb_);                                 \
        short8_t b1 = *(const short8_t*)(Bb_ + 2048);                          \
        acc0 = __builtin_amdgcn_mfma_f32_16x16x32_bf16(af, b0, acc0, 0, 0, 0); \
        acc1 = __builtin_amdgcn_mfma_f32_16x16x32_bf16(af, b1, acc1, 0, 0, 0); \
    } while (0)

        f32x4 acc0 = {0, 0, 0, 0}, acc1 = {0, 0, 0, 0};

        STAGE(0, 0); STAGE(1, 1);      // 6 outstanding per wave
        int csl = 0;
        #pragma unroll
        for (int c = 0; c < 32; ++c) {
            if (c + 2 < 32) STAGE(c + 2, (c + 2) % 3);   // 9 outstanding
            if (c < 30)       WAITV(6);                  // chunk c landed; 2 in flight
            else if (c == 30) WAITV(3);
            else              WAITV(0);
            BAR();
            CSTEP(0, o00, o01);
            CSTEP(1, o10, o11);
            BAR();
            csl = (csl == 2) ? 0 : csl + 1;
        }
#undef STAGE
#undef CSTEP

        // epilogue: bias + scatter to routed rows
        #pragma unroll
        for (int n = 0; n < 2; ++n) {
            f32x4 v = n ? acc1 : acc0;
            int col = nh * 32 + n * 16 + lr;
            if (col < NOUT) {
                #pragma unroll
                for (int j = 0; j < 4; ++j) {
                    int row = mt * 16 + lq * 4 + j;
                    if (row < nv) {
                        int smp = sRow[row];
                        if (col < NR) out[smp * NR + col] = v[j] + breg[g * NR + col];
                        else          out[B6 + smp * NKC + (col - NR)] = v[j] + bcls[g * NKC + (col - NR)];
                    }
                }
            }
        }
        __syncthreads();   // protect sRow before next tile
    }
}

// ---- tier-3 GEMM (proven R3 path, no blob needed) ----
__launch_bounds__(256, 3)
__global__ void gemm_kernel(const float* __restrict__ feats,
                            const float* __restrict__ Wreg, const float* __restrict__ breg,
                            const float* __restrict__ Wcls, const float* __restrict__ bcls,
                            const int* __restrict__ counts, const int* __restrict__ perm,
                            float* __restrict__ out, int stride) {
    __shared__ __align__(16) short Bsh[2][64][LROW];
    __shared__ int sRow[BM];

    int ts[NG + 1]; ts[0] = 0;
    int off[NG]; int acc = 0;
    #pragma unroll
    for (int gg = 0; gg < NG; ++gg) {
        int c = counts[gg];
        off[gg] = stride ? gg * stride : acc;
        acc += c;
        ts[gg + 1] = ts[gg] + (c + BM - 1) / BM;
    }
    int b = blockIdx.x;
    if (b >= ts[NG]) return;
    int g = 0;
    #pragma unroll
    for (int gg = 0; gg < NG; ++gg) if (b >= ts[gg + 1]) g = gg + 1;
    int gcnt  = counts[g];
    int goff  = off[g];
    int rbase = (b - ts[g]) * BM;
    int nvalid = gcnt - rbase; if (nvalid > BM) nvalid = BM;

    int tid = threadIdx.x;
    if (tid < BM) {
        int r = rbase + tid;
        if (r >= gcnt) r = gcnt - 1;
        sRow[tid] = perm[goff + r];
    }
    __syncthreads();

    int rB = tid >> 2;
    int cq = tid & 3;
    const float* wsrc = nullptr;
    if (rB < NR)        wsrc = Wreg + ((size_t)g * NR + rB) * ND + cq * 32;
    else if (rB < NOUT) wsrc = Wcls + ((size_t)g * NKC + (rB - NR)) * ND + cq * 32;

    int w = tid >> 6, l = tid & 63, lr = l & 15, lq = l >> 4;
    int mt = w & 1, nh = w >> 1;
    const float* aptr = feats + (size_t)sRow[mt * 16 + lr] * ND + lq * 8;
    const short* brp = (const short*)&Bsh[0][0][0] + (nh * 32 + lr) * LROW + lq * 8;

    f32x4 acc0 = {0, 0, 0, 0}, acc1 = {0, 0, 0, 0};
    float4 rb[8];

    if (wsrc) {
        #pragma unroll
        for (int i = 0; i < 8; ++i) rb[i] = *(const float4*)(wsrc + 4 * i);
    } else {
        #pragma unroll
        for (int i = 0; i < 8; ++i) rb[i] = make_float4(0.f, 0.f, 0.f, 0.f);
    }
    {
        short* bw = &Bsh[0][rB][cq * 32];
        #pragma unroll
        for (int j = 0; j < 4; ++j) *(short8_t*)(bw + 8 * j) = cvt8(rb[2 * j], rb[2 * j + 1]);
    }
    __syncthreads();

    #pragma unroll
    for (int c = 0; c < NCH; ++c) {
        const int cur = c & 1, nxt = cur ^ 1;
        if (c + 1 < NCH && wsrc) {
            const float* s = wsrc + (c + 1) * KC;
            #pragma unroll
            for (int i = 0; i < 8; ++i) rb[i] = *(const float4*)(s + 4 * i);
        }
        const short* bp = brp + cur * (64 * LROW);
        const float* ap = aptr + c * KC;
        #pragma unroll
        for (int ks = 0; ks < 4; ++ks) {
            float4 a0 = *(const float4*)(ap + ks * 32);
            float4 a1 = *(const float4*)(ap + ks * 32 + 4);
            short8_t af = cvt8(a0, a1);
            short8_t b0 = *(const short8_t*)(bp + ks * 32);
            short8_t b1 = *(const short8_t*)(bp + 16 * LROW + ks * 32);
            acc0 = __builtin_amdgcn_mfma_f32_16x16x32_bf16(af, b0, acc0, 0, 0, 0);
            acc1 = __builtin_amdgcn_mfma_f32_16x16x32_bf16(af, b1, acc1, 0, 0, 0);
        }
        if (c + 1 < NCH && wsrc) {
            short* bw = &Bsh[nxt][rB][cq * 32];
            #pragma unroll
            for (int j = 0; j < 4; ++j) *(short8_t*)(bw + 8 * j) = cvt8(rb[2 * j], rb[2 * j + 1]);
        } else if (c + 1 < NCH) {
            short8_t z = {0,0,0,0,0,0,0,0};
            short* bw = &Bsh[nxt][rB][cq * 32];
            #pragma unroll
            for (int j = 0; j < 4; ++j) *(short8_t*)(bw + 8 * j) = z;
        }
        __syncthreads();
    }

    const int B6 = NB * NR;
    #pragma unroll
    for (int n = 0; n < 2; ++n) {
        f32x4 v = n ? acc1 : acc0;
        int col = nh * 32 + n * 16 + lr;
        if (col < NOUT) {
            #pragma unroll
            for (int j = 0; j < 4; ++j) {
                int row = mt * 16 + lq * 4 + j;
                if (row < nvalid) {
                    int smp = sRow[row];
                    if (col < NR) out[smp * NR + col] = v[j] + breg[g * NR + col];
                    else          out[B6 + smp * NKC + (col - NR)] = v[j] + bcls[g * NKC + (col - NR)];
                }
            }
        }
    }
}

// ---- tier-4: exact fp32, one wave per sample ----
__global__ void fallback_kernel(const float* __restrict__ feats, const int* __restrict__ roi,
                                const float* __restrict__ Wreg, const float* __restrict__ breg,
                                const float* __restrict__ Wcls, const float* __restrict__ bcls,
                                float* __restrict__ out) {
    int i = blockIdx.x;
    int lane = threadIdx.x;
    int g = roi[i];
    const float* frow = feats + (size_t)i * ND;
    float f[32];
    #pragma unroll
    for (int q = 0; q < 32; ++q) f[q] = frow[lane + 64 * q];
    for (int o = 0; o < NOUT; ++o) {
        const float* wrow = (o < NR) ? Wreg + ((size_t)g * NR + o) * ND
                                     : Wcls + ((size_t)g * NKC + (o - NR)) * ND;
        float p = 0.f;
        #pragma unroll
        for (int q = 0; q < 32; ++q) p += f[q] * wrow[lane + 64 * q];
        #pragma unroll
        for (int s = 32; s; s >>= 1) p += __shfl_xor(p, s);
        if (lane == 0) {
            if (o < NR) out[i * NR + o] = p + breg[g * NR + o];
            else        out[NB * NR + i * NKC + (o - NR)] = p + bcls[g * NKC + (o - NR)];
        }
    }
}

extern "C" void kernel_launch(void* const* d_in, const int* in_sizes, int n_in,
                              void* d_out, int out_size, void* d_ws, size_t ws_size,
                              hipStream_t stream) {
    const float* feats = (const float*)d_in[0];
    const int*   roi   = (const int*)d_in[1];
    const float* Wreg  = (const float*)d_in[2];
    const float* breg  = (const float*)d_in[3];
    const float* Wcls  = (const float*)d_in[4];
    const float* bcls  = (const float*)d_in[5];
    float* out = (float*)d_out;

    const size_t wbfBytes = (size_t)NG * 131072 * 2;              // 2 MB blob
    const size_t need_t1 = wbfBytes + 256 + (size_t)NG * NB * 4;  // blob + fixed-stride perm
    const size_t need_t3 = 256 + (size_t)NB * 4;                  // packed-perm path

    if (ws_size >= need_t1) {
        short* Wbf = (short*)d_ws;
        int* cnt   = (int*)((char*)d_ws + wbfBytes);
        int* qhead = cnt + 8;
        int* perm  = cnt + 64;
        hipMemsetAsync(cnt, 0, 64, stream);   // cnt[0..8) + qhead
        prep_kernel<<<576, 256, 0, stream>>>(roi, cnt, perm, Wreg, Wcls, Wbf);
        gemm_q_kernel<<<512, 512, 0, stream>>>(feats, Wbf, breg, bcls, cnt, perm, qhead, out);
    } else if (ws_size >= need_t3) {
        int* counts = (int*)d_ws;
        int* ranks  = counts + 8;
        int* perm   = counts + 64;
        hipMemsetAsync(counts, 0, 16 * sizeof(int), stream);
        hist_kernel<<<NB / 256, 256, 0, stream>>>(roi, counts);
        scatter_kernel<<<NB / 256, 256, 0, stream>>>(roi, counts, ranks, perm);
        gemm_kernel<<<MAXT, 256, 0, stream>>>(feats, Wreg, breg, Wcls, bcls, counts, perm, out, 0);
    } else {
        fallback_kernel<<<NB, 64, 0, stream>>>(feats, roi, Wreg, breg, Wcls, bcls, out);
    }
}